// Round 12
// baseline (271.256 us; speedup 1.0000x reference)
//
#include <hip/hip_runtime.h>
#include <hip/hip_bf16.h>
#include <cmath>

#define NB 4
#define NS 1024
#define ND 1024
#define NH 16
#define NDH 64
#define NKSP 32
#define SCALE 0.125f      // 1/sqrt(64)
#define LOG2E 1.44269504f
#define SCALE2 (SCALE * LOG2E)

typedef __attribute__((ext_vector_type(8))) short bf16x8;
typedef __attribute__((ext_vector_type(4))) float f32x4;
typedef unsigned long long u64;

#define AS1 __attribute__((address_space(1)))
#define AS3 __attribute__((address_space(3)))

__device__ __forceinline__ void gl_lds16(const void* g, void* l) {
    __builtin_amdgcn_global_load_lds((const AS1 void*)g, (AS3 void*)l, 16, 0, 0);
}

__device__ __forceinline__ ushort f2bf(float f) {
    union { __hip_bfloat16 h; ushort u; } cv;
    cv.h = __float2bfloat16(f);
    return cv.u;
}
__device__ __forceinline__ float bf2f(ushort u) {
    union { unsigned int i; float f; } cv;
    cv.i = ((unsigned int)u) << 16;
    return cv.f;
}
__device__ __forceinline__ float fexp2(float x) {
    return __builtin_amdgcn_exp2f(x);   // v_exp_f32 (base-2)
}

// ---------------------------------------------------------------------------
// y=0: x->bf16 (4096 blocks); y=1..4: W->bf16 (1024 blocks);
// y=5: pack pmask into bitwords (4096 blocks, one wave per u64 word).
// ---------------------------------------------------------------------------
__global__ __launch_bounds__(256)
void f2bf_multi(const float* __restrict__ x,
                const float* __restrict__ w0, const float* __restrict__ w1,
                const float* __restrict__ w2, const float* __restrict__ w3,
                const int* __restrict__ pm,
                ushort* __restrict__ xo,
                ushort* __restrict__ o0, ushort* __restrict__ o1,
                ushort* __restrict__ o2, ushort* __restrict__ o3,
                u64* __restrict__ bm)
{
    int y = blockIdx.y;
    if (y == 5) {
        int word = blockIdx.x * 4 + (threadIdx.x >> 6);
        int lane = threadIdx.x & 63;
        int row  = word >> 4, wcol = word & 15;
        int v = pm[(size_t)row * NS + wcol * 64 + lane];
        u64 b = __ballot(v != 0);
        if (lane == 0) bm[word] = b;
        return;
    }
    const float* src; ushort* dst; int nblk;
    if (y == 0)      { src = x;  dst = xo; nblk = 4096; }
    else if (y == 1) { src = w0; dst = o0; nblk = 1024; }
    else if (y == 2) { src = w1; dst = o1; nblk = 1024; }
    else if (y == 3) { src = w2; dst = o2; nblk = 1024; }
    else             { src = w3; dst = o3; nblk = 1024; }
    if (blockIdx.x >= (unsigned)nblk) return;
    int i = (blockIdx.x * 256 + threadIdx.x) * 4;
    float4 v = *(const float4*)&src[i];
    ushort4 o;
    o.x = f2bf(v.x); o.y = f2bf(v.y); o.z = f2bf(v.z); o.w = f2bf(v.w);
    *(ushort4*)&dst[i] = o;
}

// ---------------------------------------------------------------------------
// Fused QKV GEMM (direct-scatter epilogue; V also writes Vt).
// grid (24,32): blockIdx.x: [0,8)=Q [8,16)=K [16,24)=V.
// ---------------------------------------------------------------------------
__global__ __launch_bounds__(256)
void gemm_qkv(const ushort* __restrict__ xb,
              const ushort* __restrict__ Wqb, const ushort* __restrict__ Wkb,
              const ushort* __restrict__ Wvb,
              const float* __restrict__ bq, const float* __restrict__ bk,
              const float* __restrict__ bv,
              ushort* __restrict__ Qo, ushort* __restrict__ Ko,
              ushort* __restrict__ Vo, ushort* __restrict__ Vto)
{
    constexpr int K = ND;
    __shared__ __attribute__((aligned(16))) ushort As[128 * 32];
    __shared__ __attribute__((aligned(16))) ushort Bs[128 * 32];

    const int tid  = threadIdx.x;
    const int lane = tid & 63, w = tid >> 6;
    const int wm = w >> 1, wn = w & 1;
    const int which = blockIdx.x >> 3;
    const int n0 = (blockIdx.x & 7) * 128;
    const int m0 = blockIdx.y * 128;
    const int quad = lane >> 4, l16 = lane & 15;

    const ushort* W = (which == 0) ? Wqb : (which == 1) ? Wkb : Wvb;
    const float* bias = (which == 0) ? bq : (which == 1) ? bk : bv;
    ushort* Out = (which == 0) ? Qo : (which == 1) ? Ko : Vo;

    f32x4 acc[4][4] = {};

    for (int k0 = 0; k0 < K; k0 += 32) {
        __syncthreads();
#pragma unroll
        for (int u = 0; u < 2; ++u) {
            int t0 = u * 256 + w * 64;
            int t  = t0 + lane;
            int row = t >> 2, kc = (t & 3) * 8;
            gl_lds16(xb + (size_t)(m0 + row) * K + k0 + kc, &As[t0 * 8]);
            gl_lds16(W  + (size_t)(n0 + row) * K + k0 + kc, &Bs[t0 * 8]);
        }
        __syncthreads();

        bf16x8 af[4], bfr[4];
#pragma unroll
        for (int mt = 0; mt < 4; ++mt)
            af[mt] = *(const bf16x8*)&As[(wm*64 + mt*16 + l16) * 32 + quad*8];
#pragma unroll
        for (int nt = 0; nt < 4; ++nt)
            bfr[nt] = *(const bf16x8*)&Bs[(wn*64 + nt*16 + l16) * 32 + quad*8];
#pragma unroll
        for (int mt = 0; mt < 4; ++mt)
#pragma unroll
            for (int nt = 0; nt < 4; ++nt)
                acc[mt][nt] = __builtin_amdgcn_mfma_f32_16x16x32_bf16(
                    af[mt], bfr[nt], acc[mt][nt], 0, 0, 0);
    }

#pragma unroll
    for (int nt = 0; nt < 4; ++nt) {
        int n = n0 + wn*64 + nt*16 + l16;
        float bz = bias[n];
        int hh = n >> 6, dh = n & 63;
#pragma unroll
        for (int mt = 0; mt < 4; ++mt) {
#pragma unroll
            for (int rg = 0; rg < 4; ++rg) {
                int m = m0 + wm*64 + mt*16 + quad*4 + rg;
                int b = m >> 10, s = m & (NS - 1);
                ushort val = f2bf(acc[mt][nt][rg] + bz);
                Out[(((size_t)(b*NH + hh))*NS + s)*NDH + dh] = val;
                if (which == 2)
                    Vto[(((size_t)(b*NH + hh))*NDH + dh)*NS + s] = val;
            }
        }
    }
}

// ---------------------------------------------------------------------------
// Output GEMM: 64x128 tile -> 512 blocks.
// ---------------------------------------------------------------------------
__global__ __launch_bounds__(256)
void gemm_out(const ushort* __restrict__ A, const ushort* __restrict__ W,
              const float* __restrict__ bias, float* __restrict__ Cout)
{
    constexpr int K = ND;
    __shared__ __attribute__((aligned(16))) ushort As[64 * 32];
    __shared__ __attribute__((aligned(16))) ushort Bs[128 * 32];

    const int tid  = threadIdx.x;
    const int lane = tid & 63, w = tid >> 6;
    const int wm = w & 1, wn = w >> 1;
    const int m0 = blockIdx.y * 64, n0 = blockIdx.x * 128;
    const int quad = lane >> 4, l16 = lane & 15;

    f32x4 acc[2][4] = {};

    for (int k0 = 0; k0 < K; k0 += 32) {
        __syncthreads();
        {
            int t0 = w * 64;
            int t  = t0 + lane;
            int row = t >> 2, kc = (t & 3) * 8;
            gl_lds16(A + (size_t)(m0 + row) * K + k0 + kc, &As[t0 * 8]);
        }
#pragma unroll
        for (int u = 0; u < 2; ++u) {
            int t0 = u * 256 + w * 64;
            int t  = t0 + lane;
            int row = t >> 2, kc = (t & 3) * 8;
            gl_lds16(W + (size_t)(n0 + row) * K + k0 + kc, &Bs[t0 * 8]);
        }
        __syncthreads();

        bf16x8 af[2], bfr[4];
#pragma unroll
        for (int mt = 0; mt < 2; ++mt)
            af[mt] = *(const bf16x8*)&As[(wm*32 + mt*16 + l16) * 32 + quad*8];
#pragma unroll
        for (int nt = 0; nt < 4; ++nt)
            bfr[nt] = *(const bf16x8*)&Bs[(wn*64 + nt*16 + l16) * 32 + quad*8];
#pragma unroll
        for (int mt = 0; mt < 2; ++mt)
#pragma unroll
            for (int nt = 0; nt < 4; ++nt)
                acc[mt][nt] = __builtin_amdgcn_mfma_f32_16x16x32_bf16(
                    af[mt], bfr[nt], acc[mt][nt], 0, 0, 0);
    }

#pragma unroll
    for (int nt = 0; nt < 4; ++nt) {
        int n = n0 + wn*64 + nt*16 + l16;
        float bz = bias[n];
#pragma unroll
        for (int mt = 0; mt < 2; ++mt) {
#pragma unroll
            for (int rg = 0; rg < 4; ++rg) {
                int m = m0 + wm*32 + mt*16 + quad*4 + rg;
                Cout[(size_t)m * ND + n] = acc[mt][nt][rg] + bz;
            }
        }
    }
}

// ---------------------------------------------------------------------------
// MFMA flash attention, 128 q-rows/block, grid 512. Dense path = R11
// (K/V fragments straight from global, S^T trick, base-2 exp, ones-MFMA
// lsum, one barrier). Sparse path REWRITTEN for coalescing: lane =
// (key-slot klo = lane>>3) x (chunk ch = lane&7); one q-row at a time
// (32 rows/wave); K/V rows read contiguously by 8 ch-lanes; dot reduced
// via shfl_xor(1,2,4); softmax across keys via shfl_xor(8,16,32);
// coalesced 8-lane b128 output store.
// ---------------------------------------------------------------------------
__global__ __launch_bounds__(256)
void attn_kernel(const ushort* __restrict__ Qb, const ushort* __restrict__ Kb,
                 const ushort* __restrict__ Vb, const ushort* __restrict__ Vt,
                 const u64* __restrict__ bm,
                 const int* __restrict__ pidx, const int* __restrict__ pimask,
                 const float* __restrict__ u_prev, ushort* __restrict__ OA)
{
    __shared__ __attribute__((aligned(16))) ushort Ps[128 * 72];
    __shared__ __attribute__((aligned(16))) u64    MW[128 * 16];

    const int tid  = threadIdx.x;
    const int lane = tid & 63, w = tid >> 6;
    const int quad = lane >> 4, l16 = lane & 15;

    const int id    = blockIdx.x;
    const int xcd   = id & 7;
    const int t5    = id >> 3;            // 0..63
    const int qtile = t5 & 7;
    const int head  = (t5 >> 3) * 8 + xcd;
    const int b = head >> 4, h = head & 15;
    const int s0 = qtile * 128;

    const float lam = 10.0f * __expf(-5.0f * u_prev[b]);
    const bool sparse = (lam >= 1.0f);

    const size_t bh = (size_t)b * NH + h;
    const ushort* Qh  = Qb + bh * NS * NDH;
    const ushort* Kh  = Kb + bh * NS * NDH;
    const ushort* Vh  = Vb + bh * NS * NDH;
    const ushort* Vth = Vt + bh * NDH * NS;

    if (!sparse) {
        const float nlam2 = -lam * LOG2E;   // base-2 bias

        // stage mask words for rows s0..s0+127 (2048 u64 = 16 KB)
#pragma unroll
        for (int u = 0; u < 8; ++u) {
            int idx = u * 256 + tid;
            MW[idx] = bm[(size_t)s0 * 16 + idx];
        }
        __syncthreads();   // the only block barrier

        // Q fragments (serve as B-operand = Q^T)
        bf16x8 qf[2][2];
#pragma unroll
        for (int qh = 0; qh < 2; ++qh)
#pragma unroll
            for (int kk = 0; kk < 2; ++kk)
                qf[qh][kk] = *(const bf16x8*)
                    &Qh[(size_t)(s0 + w*32 + qh*16 + l16) * NDH + kk*32 + quad*8];

        union { bf16x8 v; ushort s[8]; } ones;
#pragma unroll
        for (int i = 0; i < 8; ++i) ones.s[i] = 0x3F80;  // bf16 1.0

        f32x4 o_acc[2][4] = {};
        f32x4 l_acc[2] = {};

        for (int kt = 0; kt < 16; ++kt) {
            // K/V fragments straight from global (identical across waves ->
            // L1 broadcast; tiles L2-resident via XCD swizzle)
            bf16x8 kf[4][2], vf[4][2];
#pragma unroll
            for (int nt = 0; nt < 4; ++nt)
#pragma unroll
                for (int kk = 0; kk < 2; ++kk) {
                    kf[nt][kk] = *(const bf16x8*)
                        &Kh[(size_t)(kt*64 + nt*16 + l16) * NDH + kk*32 + quad*8];
                    vf[nt][kk] = *(const bf16x8*)
                        &Vth[(size_t)(nt*16 + l16) * NS + kt*64 + kk*32 + quad*8];
                }

#pragma unroll
            for (int qh = 0; qh < 2; ++qh) {
                const int qrow = w*32 + qh*16 + l16;

                // S^T: mfma(K-frag, Q-frag) -> row=key_local, col=query
                f32x4 s_acc[4] = {};
#pragma unroll
                for (int nt = 0; nt < 4; ++nt)
#pragma unroll
                    for (int kk = 0; kk < 2; ++kk)
                        s_acc[nt] = __builtin_amdgcn_mfma_f32_16x16x32_bf16(
                            kf[nt][kk], qf[qh][kk], s_acc[nt], 0, 0, 0);

                // mask (1 word/lane) + base-2 exp; P row-major via b64 writes
                u64 wq = MW[qrow * 16 + kt] >> (quad * 4);
#pragma unroll
                for (int nt = 0; nt < 4; ++nt) {
                    ushort4 pk;
                    float p0 = fexp2(fmaf(s_acc[nt][0], SCALE2,
                         ((wq >> (nt*16 + 0)) & 1ULL) ? 0.f : nlam2));
                    float p1 = fexp2(fmaf(s_acc[nt][1], SCALE2,
                         ((wq >> (nt*16 + 1)) & 1ULL) ? 0.f : nlam2));
                    float p2 = fexp2(fmaf(s_acc[nt][2], SCALE2,
                         ((wq >> (nt*16 + 2)) & 1ULL) ? 0.f : nlam2));
                    float p3 = fexp2(fmaf(s_acc[nt][3], SCALE2,
                         ((wq >> (nt*16 + 3)) & 1ULL) ? 0.f : nlam2));
                    pk.x = f2bf(p0); pk.y = f2bf(p1);
                    pk.z = f2bf(p2); pk.w = f2bf(p3);
                    *(ushort4*)&Ps[qrow*72 + nt*16 + quad*4] = pk;
                }

                // PV + lsum (wave-internal P round-trip; no barrier)
                bf16x8 pf[2];
#pragma unroll
                for (int kk = 0; kk < 2; ++kk)
                    pf[kk] = *(const bf16x8*)&Ps[qrow*72 + kk*32 + quad*8];
#pragma unroll
                for (int kk = 0; kk < 2; ++kk) {
                    l_acc[qh] = __builtin_amdgcn_mfma_f32_16x16x32_bf16(
                        pf[kk], ones.v, l_acc[qh], 0, 0, 0);
#pragma unroll
                    for (int nt = 0; nt < 4; ++nt)
                        o_acc[qh][nt] = __builtin_amdgcn_mfma_f32_16x16x32_bf16(
                            pf[kk], vf[nt][kk], o_acc[qh][nt], 0, 0, 0);
                }
            }
        }

        // epilogue (o_acc: row=query quad*4+rg, col=dh nt*16+l16)
#pragma unroll
        for (int qh = 0; qh < 2; ++qh) {
            float inv[4];
#pragma unroll
            for (int rg = 0; rg < 4; ++rg) inv[rg] = 1.f / l_acc[qh][rg];
#pragma unroll
            for (int nt = 0; nt < 4; ++nt)
#pragma unroll
                for (int rg = 0; rg < 4; ++rg) {
                    int m = w*32 + qh*16 + quad*4 + rg;
                    OA[((size_t)b*NS + s0 + m)*ND + h*NDH + nt*16 + l16] =
                        f2bf(o_acc[qh][nt][rg] * inv[rg]);
                }
        }
    } else {
        // ------------- sparse path: wave-cooperative, coalesced -----------
        // lane = klo(=lane>>3, key slot) x ch(=lane&7, 16B chunk of row).
        // One q-row per iteration; 32 rows per wave.
        const int klo = lane >> 3;
        const int ch  = lane & 7;

        for (int r = 0; r < 32; ++r) {
            const int row = s0 + w*32 + r;

            // Q chunk for this lane (shared across passes)
            float q[8];
            {
                union { bf16x8 v; ushort s[8]; } qv;
                qv.v = *(const bf16x8*)&Qh[(size_t)row * NDH + ch*8];
#pragma unroll
                for (int i = 0; i < 8; ++i) q[i] = bf2f(qv.s[i]);
            }

            float sc[4];
            int   kvr[4];
#pragma unroll
            for (int pass = 0; pass < 4; ++pass) {
                int j  = pass*8 + klo;
                int mv = pimask[(size_t)row * NKSP + j];
                int kv = pidx[(size_t)row * NKSP + j];
                kvr[pass] = kv;
                float dot = 0.f;
                if (mv) {
                    union { bf16x8 v; ushort s[8]; } kc;
                    kc.v = *(const bf16x8*)&Kh[(size_t)kv * NDH + ch*8];
#pragma unroll
                    for (int i = 0; i < 8; ++i)
                        dot = fmaf(q[i], bf2f(kc.s[i]), dot);
                }
                // reduce partial dot across the 8 ch-lanes (same j)
                dot += __shfl_xor(dot, 1);
                dot += __shfl_xor(dot, 2);
                dot += __shfl_xor(dot, 4);
                sc[pass] = mv ? dot * SCALE : -INFINITY;
            }

            // softmax over 32 keys: in-lane over passes, then across klo
            float mx = fmaxf(fmaxf(sc[0], sc[1]), fmaxf(sc[2], sc[3]));
            mx = fmaxf(mx, __shfl_xor(mx, 8));
            mx = fmaxf(mx, __shfl_xor(mx, 16));
            mx = fmaxf(mx, __shfl_xor(mx, 32));
            float p[4], ps = 0.f;
#pragma unroll
            for (int pass = 0; pass < 4; ++pass) {
                p[pass] = __expf(sc[pass] - mx);   // exp(-inf)=0 for masked
                ps += p[pass];
            }
            ps += __shfl_xor(ps, 8);
            ps += __shfl_xor(ps, 16);
            ps += __shfl_xor(ps, 32);
            float inv = 1.f / ps;

            // PV: each lane accumulates its 8-dh chunk over its 4 keys
            float o[8] = {0.f,0.f,0.f,0.f,0.f,0.f,0.f,0.f};
#pragma unroll
            for (int pass = 0; pass < 4; ++pass) {
                if (p[pass] != 0.f) {
                    union { bf16x8 v; ushort s[8]; } vc;
                    vc.v = *(const bf16x8*)&Vh[(size_t)kvr[pass] * NDH + ch*8];
#pragma unroll
                    for (int i = 0; i < 8; ++i)
                        o[i] = fmaf(p[pass], bf2f(vc.s[i]), o[i]);
                }
            }
            // reduce chunk partials across the 8 klo-lanes
#pragma unroll
            for (int m = 8; m <= 32; m <<= 1)
#pragma unroll
                for (int i = 0; i < 8; ++i)
                    o[i] += __shfl_xor(o[i], m);

            // coalesced store: lanes with klo==0 write their 16B chunk
            if (klo == 0) {
                union { bf16x8 v; ushort s[8]; } ov;
#pragma unroll
                for (int i = 0; i < 8; ++i) ov.s[i] = f2bf(o[i] * inv);
                *(bf16x8*)&OA[((size_t)b*NS + row)*ND + h*NDH + ch*8] = ov.v;
            }
        }
    }
}

// ---------------------------------------------------------------------------
extern "C" void kernel_launch(void* const* d_in, const int* in_sizes, int n_in,
                              void* d_out, int out_size, void* d_ws, size_t ws_size,
                              hipStream_t stream)
{
    const float* x      = (const float*)d_in[0];
    const int*   pmask  = (const int*)  d_in[1];
    const int*   pidx   = (const int*)  d_in[2];
    const int*   pimask = (const int*)  d_in[3];
    const float* u_prev = (const float*)d_in[4];
    const float* Wq     = (const float*)d_in[5];
    const float* bq     = (const float*)d_in[6];
    const float* Wk     = (const float*)d_in[7];
    const float* bk     = (const float*)d_in[8];
    const float* Wv     = (const float*)d_in[9];
    const float* bv     = (const float*)d_in[10];
    const float* Wo     = (const float*)d_in[11];
    const float* bo     = (const float*)d_in[12];
    float* out = (float*)d_out;

    const size_t QSZ = (size_t)NB * NH * NS * NDH;   // 4,194,304 elements
    const size_t WSZ = (size_t)ND * ND;              // 1,048,576 elements
    ushort* xb  = (ushort*)d_ws;        // bf16 x              (8 MB)
    ushort* Qw  = xb  + QSZ;            // bf16 Q (b,h,s,dh)   (8 MB)
    ushort* Kw  = Qw  + QSZ;            // bf16 K              (8 MB)
    ushort* Vw  = Kw  + QSZ;            // bf16 V              (8 MB)
    ushort* Vtw = Vw  + QSZ;            // bf16 V^T (b,h,dh,s) (8 MB)
    ushort* Awb = Vtw + QSZ;            // bf16 attn out       (8 MB)
    ushort* Wqb = Awb + QSZ;            // bf16 weights (2 MB each)
    ushort* Wkb = Wqb + WSZ;
    ushort* Wvb = Wkb + WSZ;
    ushort* Wob = Wvb + WSZ;
    u64*    bmw = (u64*)(Wob + WSZ);    // packed mask (128 KB)

    f2bf_multi<<<dim3(4096, 6), 256, 0, stream>>>(
        x, Wq, Wk, Wv, Wo, pmask, xb, Wqb, Wkb, Wvb, Wob, bmw);

    gemm_qkv<<<dim3(24, 32), 256, 0, stream>>>(
        xb, Wqb, Wkb, Wvb, bq, bk, bv, Qw, Kw, Vw, Vtw);

    attn_kernel<<<512, 256, 0, stream>>>(
        Qw, Kw, Vw, Vtw, bmw, pidx, pimask, u_prev, Awb);

    gemm_out<<<dim3(ND/128, (NB*NS)/64), 256, 0, stream>>>(Awb, Wob, bo, out);
}